// Round 14
// baseline (173.596 us; speedup 1.0000x reference)
//
#include <hip/hip_runtime.h>
#include <hip/hip_bf16.h>
#include <cstdint>

#define NROIS  4000
#define NCH    128
#define NBINS  49
#define N_POSA 1000
#define N_NEGA 200000
#define POOLN  20000
#define HBITS_A 13
#define ABINS  8192
#define PBINS  4096
#define SUBN   4096
#define NPREP  107           // 106 prep + 1 bucket
#define NRANKA 512
#define NRANKP 157           // ceil(2*POOLN/256)
#define TPAD   136
#define NTRA   672           // L1+L2+L3 transpose blocks (both batches)
#define NTRB   2048          // L0 transpose blocks (both batches)

// tl (channels-last bf16 fmaps) element offsets per level
#define L0OFF 0ull
#define L1OFF 16777216ull
#define L2OFF 20971520ull
#define L3OFF 22020096ull
#define TLELEMS 22282240ull

// ---------------------------------------------------------------------------
// threefry2x32 (device) — exact JAX semantics
// ---------------------------------------------------------------------------
__device__ __forceinline__ uint32_t rotl32d(uint32_t v, int r) { return (v << r) | (v >> (32-r)); }

__device__ void tf2x32(uint32_t k0, uint32_t k1, uint32_t& x0, uint32_t& x1)
{
    const uint32_t ks2 = k0 ^ k1 ^ 0x1BD11BDAu;
    const int R0[4] = {13,15,26,6};
    const int R1[4] = {17,29,16,24};
    x0 += k0; x1 += k1;
#pragma unroll
    for (int r = 0; r < 4; ++r) { x0 += x1; x1 = rotl32d(x1, R0[r]); x1 ^= x0; }
    x0 += k1;  x1 += ks2 + 1u;
#pragma unroll
    for (int r = 0; r < 4; ++r) { x0 += x1; x1 = rotl32d(x1, R1[r]); x1 ^= x0; }
    x0 += ks2; x1 += k0 + 2u;
#pragma unroll
    for (int r = 0; r < 4; ++r) { x0 += x1; x1 = rotl32d(x1, R0[r]); x1 ^= x0; }
    x0 += k0;  x1 += k1 + 3u;
#pragma unroll
    for (int r = 0; r < 4; ++r) { x0 += x1; x1 = rotl32d(x1, R1[r]); x1 ^= x0; }
    x0 += k1;  x1 += ks2 + 4u;
#pragma unroll
    for (int r = 0; r < 4; ++r) { x0 += x1; x1 = rotl32d(x1, R0[r]); x1 ^= x0; }
    x0 += ks2; x1 += k0 + 5u;
}

__device__ __forceinline__ unsigned int monobits(float x) {
    unsigned int u = __float_as_uint(x);
    return (u & 0x80000000u) ? ~u : (u | 0x80000000u);
}

__device__ __forceinline__ unsigned short f2bf(float x) {
    union { __hip_bfloat16 h; unsigned short u; } c;
    c.h = __float2bfloat16(x);
    return c.u;
}

__device__ __forceinline__ int roi_level(const float* __restrict__ rois, int n)
{
    const float h = rois[n*5+2] - rois[n*5+0];
    const float w = rois[n*5+3] - rois[n*5+1];
    const float lraw = rintf(4.0f + log2f(sqrtf(h*w + 1e-12f)));
    int lvl = (int)lraw; return lvl < 0 ? 0 : (lvl > 3 ? 3 : lvl);
}

// ---------------------------------------------------------------------------
// k_zero: zero hists (16384 u32) + resvA + resvP1/P2 + cnt.
// ---------------------------------------------------------------------------
__global__ void k_zero(unsigned int* __restrict__ h, unsigned int* __restrict__ rA,
                       unsigned int* __restrict__ rP1, unsigned int* __restrict__ rP2,
                       unsigned int* __restrict__ cnt)
{
    const int b = blockIdx.x;
    const int i = b*256 + threadIdx.x;
    if      (b <  64) h[i] = 0u;
    else if (b <  96) rA[i - 64*256] = 0u;
    else if (b < 112) rP1[i - 96*256] = 0u;
    else              rP2[i - 112*256] = 0u;
    if (b == 0 && threadIdx.x < 2) cnt[threadIdx.x] = 0u;
}

// ---------------------------------------------------------------------------
// transpose device fn: trid in [0,2720). 64hw x 128ch tile.
// smraw >= 17408 B.
// ---------------------------------------------------------------------------
__device__ void do_transpose(int trid, const float* __restrict__ f0,
                             const float* __restrict__ f1, const float* __restrict__ f2,
                             const float* __restrict__ f3,
                             __hip_bfloat16* __restrict__ tl, unsigned char* smraw)
{
    unsigned short* s = (unsigned short*)smraw;
    const int t  = threadIdx.x;
    const int bz = trid / 1360;
    const int r  = trid - bz*1360;
    int lvl, tile;
    if      (r < 1024) { lvl = 0; tile = r; }
    else if (r < 1280) { lvl = 1; tile = r - 1024; }
    else if (r < 1344) { lvl = 2; tile = r - 1280; }
    else               { lvl = 3; tile = r - 1344; }
    const int HW = 65536 >> (2*lvl);
    const float* in = (lvl==0) ? f0 : (lvl==1) ? f1 : (lvl==2) ? f2 : f3;
    const size_t ooff = (lvl==0) ? L0OFF : (lvl==1) ? L1OFF : (lvl==2) ? L2OFF : L3OFF;
    const int hw0 = tile * 64;
    const float4* in4 = (const float4*)(in + (size_t)bz * 128 * HW);
    const int HW4 = HW >> 2;
    const int h4b = hw0 >> 2;
#pragma unroll
    for (int k = 0; k < 8; ++k) {
        const int idx = t + k*256;
        const int c   = idx >> 4;
        const int h4  = idx & 15;
        const float4 v = in4[(size_t)c * HW4 + h4b + h4];
        const int r0 = h4 * 4;
        const int cs = c ^ ((h4 & 7) << 3);
        s[(r0+0)*TPAD + cs] = f2bf(v.x);
        s[(r0+1)*TPAD + cs] = f2bf(v.y);
        s[(r0+2)*TPAD + cs] = f2bf(v.z);
        s[(r0+3)*TPAD + cs] = f2bf(v.w);
    }
    __syncthreads();
    uint4* out4 = (uint4*)(tl + ooff + (size_t)bz * (size_t)HW * 128
                                     + (size_t)hw0 * 128);
    const int rr = t >> 4;
    const int q  = t & 15;
    const int c8 = q * 8;
#pragma unroll
    for (int m = 0; m < 4; ++m) {
        const int row = rr + m*16;
        const int sw = ((row >> 2) & 7) << 3;
        out4[row*16 + q] = *(const uint4*)&s[row*TPAD + (c8 ^ sw)];
    }
}

// ---------------------------------------------------------------------------
// roi device fn: half-channel staging + uint4 taps. smraw >= 14112 B.
// ---------------------------------------------------------------------------
__device__ void do_roi(int n, const __hip_bfloat16* __restrict__ tl,
                       const float* __restrict__ rois, float* __restrict__ out,
                       unsigned char* smraw)
{
    int   (*s_a)[4] = (int(*)[4])smraw;
    float (*s_w)[4] = (float(*)[4])(smraw + 784);
    float* s_o      = (float*)(smraw + 1568);
    const int tid = threadIdx.x;

    const float ry1 = rois[n*5+0], rx1 = rois[n*5+1];
    const float ry2 = rois[n*5+2], rx2 = rois[n*5+3];
    const int   b   = (int)rois[n*5+4];
    const int lvl = roi_level(rois, n);
    const int H = 256 >> lvl;
    const size_t lbase = (lvl==0) ? L0OFF : (lvl==1) ? L1OFF : (lvl==2) ? L2OFF : L3OFF;
    const __hip_bfloat16* bp = tl + lbase + (size_t)b * (size_t)(H*H) * NCH;

    const float Hf  = (float)H;
    const float y1p = ry1*Hf, x1p = rx1*Hf, y2p = ry2*Hf, x2p = rx2*Hf;
    const float bh = (y2p - y1p) / 7.0f, bw = (x2p - x1p) / 7.0f;

    if (tid < NBINS) {
        const int py = tid / 7, px = tid % 7;
        float sy = y1p + bh*((float)py + 0.5f);
        float sx = x1p + bw*((float)px + 0.5f);
        sy = fminf(fmaxf(sy, 0.0f), Hf - 1.0f);
        sx = fminf(fmaxf(sx, 0.0f), Hf - 1.0f);
        const float y0f = floorf(sy), x0f = floorf(sx);
        const int y0 = (int)y0f, x0 = (int)x0f;
        const int y1i = min(y0+1, H-1), x1i = min(x0+1, H-1);
        const float wy = sy - y0f, wx = sx - x0f;
        s_a[tid][0] = y0 *H + x0;
        s_a[tid][1] = y0 *H + x1i;
        s_a[tid][2] = y1i*H + x0;
        s_a[tid][3] = y1i*H + x1i;
        const float omy = 1.0f - wy, omx = 1.0f - wx;
        s_w[tid][0] = omy*omx; s_w[tid][1] = omy*wx;
        s_w[tid][2] = wy *omx; s_w[tid][3] = wy *wx;
    }
    __syncthreads();

    const int c8 = tid & 7;
    const int bg = tid >> 3;
#pragma unroll
    for (int half = 0; half < 2; ++half) {
        if (half) __syncthreads();
        for (int bin = bg; bin < NBINS; bin += 32) {
            float a0=0.f,a1=0.f,a2=0.f,a3=0.f,a4=0.f,a5=0.f,a6=0.f,a7=0.f;
#pragma unroll
            for (int tap = 0; tap < 4; ++tap) {
                const uint4 v = *(const uint4*)
                    (bp + (size_t)s_a[bin][tap]*NCH + half*64 + 8*c8);
                const float wgt = s_w[bin][tap];
                a0 += __uint_as_float(v.x << 16)         * wgt;
                a1 += __uint_as_float(v.x & 0xffff0000u) * wgt;
                a2 += __uint_as_float(v.y << 16)         * wgt;
                a3 += __uint_as_float(v.y & 0xffff0000u) * wgt;
                a4 += __uint_as_float(v.z << 16)         * wgt;
                a5 += __uint_as_float(v.z & 0xffff0000u) * wgt;
                a6 += __uint_as_float(v.w << 16)         * wgt;
                a7 += __uint_as_float(v.w & 0xffff0000u) * wgt;
            }
            s_o[(8*c8+0)*NBINS + bin] = a0;
            s_o[(8*c8+1)*NBINS + bin] = a1;
            s_o[(8*c8+2)*NBINS + bin] = a2;
            s_o[(8*c8+3)*NBINS + bin] = a3;
            s_o[(8*c8+4)*NBINS + bin] = a4;
            s_o[(8*c8+5)*NBINS + bin] = a5;
            s_o[(8*c8+6)*NBINS + bin] = a6;
            s_o[(8*c8+7)*NBINS + bin] = a7;
        }
        __syncthreads();
        float4* outn = (float4*)(out + (size_t)n*(NCH*NBINS) + half*64*NBINS);
        const float4* so4 = (const float4*)s_o;
        for (int t4 = tid; t4 < (64*NBINS)/4; t4 += 256)
            outn[t4] = so4[t4];
    }
}

// ---------------------------------------------------------------------------
// k_stageA: blocks [0,ntrA): transpose L1/L2/L3 (both batches).
//           blocks [ntrA,ntrA+107): prep (perm keys+hists, OHEM hist, losses,
//           ROI level-bucketing).
// ---------------------------------------------------------------------------
__global__ __launch_bounds__(256) void k_stageA(
    const float* __restrict__ f0, const float* __restrict__ f1,
    const float* __restrict__ f2, const float* __restrict__ f3,
    __hip_bfloat16* __restrict__ tl, const float* __restrict__ rois,
    unsigned long long* __restrict__ T1, unsigned long long* __restrict__ T2,
    unsigned int* __restrict__ histA,
    unsigned int* __restrict__ histP1, unsigned int* __restrict__ histP2,
    const int* __restrict__ am, const float* __restrict__ logits,
    const float* __restrict__ pd, const float* __restrict__ td,
    float* __restrict__ prt,
    unsigned int* __restrict__ listHi, unsigned int* __restrict__ listLo,
    unsigned int* __restrict__ cnt, int ntrA)
{
    __shared__ __align__(16) unsigned char smraw[17408];
    const int bid = blockIdx.x;
    const int t   = threadIdx.x;

    if (bid < ntrA) {
        const int bz = bid / 336;
        const int rr = 1024 + (bid - bz*336);
        do_transpose(bz*1360 + rr, f0, f1, f2, f3, tl, smraw);
        return;
    }

    const int pbid = bid - ntrA;
    if (pbid < 40) {
        unsigned int* buf = (unsigned int*)smraw;   // 8192 u32 needed? no: 2*PBINS=8192 u32 = 32KB > 17408!
        // NOTE: perm histograms need 2*4096 u32 = 32 KB; use 16-bit packed halves
        // to fit 17408 B: lh[b] packs (histP1 count, histP2 count) per bin.
        unsigned int* lh = buf;                     // 4096 u32 = 16384 B
        for (int b = t; b < PBINS; b += 256) lh[b] = 0u;
        __syncthreads();
        const int i = pbid*256 + t;
        if (i < POOLN/2) {
            uint32_t a0 = 0u, a1 = 2u; tf2x32(0u, 1u, a0, a1);
            uint32_t b0 = 1u, b1 = 3u; tf2x32(0u, 1u, b0, b1);
            uint32_t c0 = 0u, c1 = 2u; tf2x32(a0, b0, c0, c1);
            uint32_t d0 = 1u, d1 = 3u; tf2x32(a0, b0, d0, d1);
            uint32_t x0 = (uint32_t)i, x1 = (uint32_t)(POOLN/2 + i);
            tf2x32(a1, b1, x0, x1);
            T1[i]           = ((unsigned long long)x0 << 32) | (unsigned)i;
            T1[POOLN/2 + i] = ((unsigned long long)x1 << 32) | (unsigned)(POOLN/2 + i);
            atomicAdd(&lh[x0 >> 20], 1u);
            atomicAdd(&lh[x1 >> 20], 1u);
            uint32_t y0 = (uint32_t)i, y1 = (uint32_t)(POOLN/2 + i);
            tf2x32(c1, d1, y0, y1);
            T2[i]           = ((unsigned long long)y0 << 32) | (unsigned)i;
            T2[POOLN/2 + i] = ((unsigned long long)y1 << 32) | (unsigned)(POOLN/2 + i);
            atomicAdd(&lh[y0 >> 20], 0x10000u);
            atomicAdd(&lh[y1 >> 20], 0x10000u);
        }
        __syncthreads();
        for (int b = t; b < PBINS; b += 256) {
            const unsigned int v = lh[b];
            if (v & 0xFFFFu)  atomicAdd(&histP1[b], v & 0xFFFFu);
            if (v >> 16)      atomicAdd(&histP2[b], v >> 16);
        }
        return;
    }
    if (pbid < 104) {
        // OHEM 13-bit histogram: 8192 bins packed as ushort pairs (16384 B)
        unsigned int* buf = (unsigned int*)smraw;   // 4096 u32
        for (int b = t; b < ABINS/2; b += 256) buf[b] = 0u;
        __syncthreads();
        for (int i = (pbid-40)*256 + t; i < N_NEGA; i += 64*256) {
            const float l0 = logits[(size_t)(N_POSA+i)*2+0];
            const float l1 = logits[(size_t)(N_POSA+i)*2+1];
            const unsigned int bin = monobits(l0 - l1) >> (32-HBITS_A);
            atomicAdd(&buf[bin >> 1], 1u << ((bin & 1) << 4));
        }
        __syncthreads();
        for (int b = t; b < ABINS/2; b += 256) {
            const unsigned int v = buf[b];
            if (v & 0xFFFFu) atomicAdd(&histA[2*b],   v & 0xFFFFu);
            if (v >> 16)     atomicAdd(&histA[2*b+1], v >> 16);
        }
        return;
    }
    if (pbid == 106) {
        // bucket ROIs by level
        for (int i = t; i < NROIS; i += 256) {
            const int lvl = roi_level(rois, i);
            if (lvl == 0) listLo[atomicAdd(&cnt[1], 1u)] = (unsigned)i;
            else          listHi[atomicAdd(&cnt[0], 1u)] = (unsigned)i;
        }
        return;
    }
    float* red = (float*)smraw;
    float s = 0.0f;
    if (pbid == 104) {
        for (int i = t; i < N_POSA; i += 256) {
            const int tgt = am[i];
            const float l0 = logits[(size_t)i*2+0], l1 = logits[(size_t)i*2+1];
            const float m = fmaxf(l0, l1);
            const float lse = logf(expf(l0-m) + expf(l1-m));
            const float lt = (tgt == 0) ? l0 : l1;
            s += (lt - m) - lse;
        }
    } else {
        for (int i = t; i < N_POSA*4; i += 256) {
            const float d = fabsf(pd[i] - td[i]);
            s += (d < 1.0f) ? 0.5f*d*d : d - 0.5f;
        }
    }
    red[t] = s;
    __syncthreads();
    for (int off = 128; off > 0; off >>= 1) {
        if (t < off) red[t] += red[t+off];
        __syncthreads();
    }
    if (t == 0) prt[pbid - 104] = red[0];
}

// ---------------------------------------------------------------------------
// 256-thread exclusive scan helper (hist -> base only)
// ---------------------------------------------------------------------------
__device__ void scan_one256(const unsigned int* __restrict__ hist,
                            unsigned int* __restrict__ base, int n, unsigned int* lds)
{
    const int t = threadIdx.x;
    const int chunk = n >> 8;
    unsigned int s = 0;
    for (int k = 0; k < chunk; ++k) s += hist[t*chunk + k];
    lds[t] = s;
    __syncthreads();
    for (int off = 1; off < 256; off <<= 1) {
        unsigned int v = (t >= off) ? lds[t-off] : 0u;
        __syncthreads();
        lds[t] += v;
        __syncthreads();
    }
    unsigned int run = (t == 0) ? 0u : lds[t-1];
    for (int k = 0; k < chunk; ++k) {
        base[t*chunk+k] = run;
        run += hist[t*chunk+k];
    }
    if (t == 255) base[n] = run;
    __syncthreads();
}

// ---------------------------------------------------------------------------
// k_stageB: blocks [0,ntrB): transpose L0 (both batches).
//           blocks [ntrB, ntrB+nslots): roi over listHi (lvl >= 1).
//           block ntrB+nslots: scans+sel. then 64 A-scatter + 79 P-scatter.
// ---------------------------------------------------------------------------
__global__ __launch_bounds__(256, 8) void k_stageB(
    const float* __restrict__ f0, const float* __restrict__ f1,
    const float* __restrict__ f2, const float* __restrict__ f3,
    __hip_bfloat16* __restrict__ tl, const float* __restrict__ rois,
    float* __restrict__ out, const float* __restrict__ logits,
    const unsigned long long* __restrict__ T1, const unsigned long long* __restrict__ T2,
    unsigned long long* __restrict__ A,
    unsigned long long* __restrict__ P1, unsigned long long* __restrict__ P2,
    const unsigned int* __restrict__ histA,
    const unsigned int* __restrict__ histP1, const unsigned int* __restrict__ histP2,
    unsigned int* __restrict__ baseA, unsigned int* __restrict__ baseP1,
    unsigned int* __restrict__ baseP2,
    unsigned int* __restrict__ resvA, unsigned int* __restrict__ resvP1,
    unsigned int* __restrict__ resvP2,
    unsigned int* __restrict__ sel,
    const unsigned int* __restrict__ listHi, const unsigned int* __restrict__ cnt,
    int ntrB, int nslots)
{
    __shared__ __align__(16) unsigned char smraw[17440];
    const int bid = blockIdx.x;
    const int t   = threadIdx.x;

    if (bid < ntrB) {
        const int bz = bid >> 10;
        do_transpose(bz*1360 + (bid & 1023), f0, f1, f2, f3, tl, smraw);
        return;
    }
    const int rid = bid - ntrB;
    if (rid < nslots) {
        if ((unsigned)rid < cnt[0]) do_roi((int)listHi[rid], tl, rois, out, smraw);
        return;
    }
    const int sbid = rid - nslots;
    if (sbid == 0) {
        unsigned int* lds = (unsigned int*)smraw;
        scan_one256(histA, baseA, ABINS, lds);
        scan_one256(histP1, baseP1, PBINS, lds);
        scan_one256(histP2, baseP2, PBINS, lds);
        const int chunk = ABINS >> 8;
        for (int k = 0; k < chunk; ++k) {
            const int bin = t*chunk + k;
            if (baseA[bin] < POOLN && baseA[bin] + histA[bin] >= POOLN)
                sel[0] = (unsigned int)bin;
        }
        return;
    }
    if (sbid <= 64) {
        const int sa = sbid - 1;
        unsigned int* lh   = (unsigned int*)smraw;            // 4096 u32 packed
        unsigned int* temp = (unsigned int*)(smraw + 16384);  // 256 u32
        unsigned int* svl  = (unsigned int*)(smraw + 17408);  // 1 u32
        for (int b = t; b < ABINS/2; b += 256) lh[b] = 0u;
        unsigned int s = 0;
        for (int k = 0; k < 32; ++k) s += histA[t*32 + k];
        temp[t] = s;
        __syncthreads();
        for (int off = 1; off < 256; off <<= 1) {
            const unsigned int v = (t >= off) ? temp[t-off] : 0u;
            __syncthreads();
            temp[t] += v;
            __syncthreads();
        }
        unsigned int run = (t == 0) ? 0u : temp[t-1];
        for (int k = 0; k < 32; ++k) {
            const int b = t*32 + k;
            const unsigned int hv = histA[b];
            if (run < POOLN && run + hv >= POOLN) svl[0] = (unsigned int)b;
            run += hv;
        }
        __syncthreads();
        const unsigned int selv = svl[0];
        const int start = sa * (N_NEGA/64);
        const int end   = start + (N_NEGA/64);
        for (int i = start + t; i < end; i += 256) {
            const float l0 = logits[(size_t)(N_POSA+i)*2+0];
            const float l1 = logits[(size_t)(N_POSA+i)*2+1];
            const unsigned int bin = monobits(l0 - l1) >> (32-HBITS_A);
            if (bin <= selv) atomicAdd(&lh[bin >> 1], 1u << ((bin & 1) << 4));
        }
        __syncthreads();
        run = (t == 0) ? 0u : temp[t-1];
        for (int k = 0; k < 32; k += 2) {
            const int b0 = t*32 + k;
            const unsigned int packed = lh[b0 >> 1];
            const unsigned int c0 = packed & 0xFFFFu, c1 = packed >> 16;
            unsigned int n0 = 0u, n1 = 0u;
            if (c0) n0 = run + atomicAdd(&resvA[b0], c0);
            run += histA[b0];
            if (c1) n1 = run + atomicAdd(&resvA[b0+1], c1);
            run += histA[b0+1];
            lh[b0 >> 1] = n0 | (n1 << 16);
        }
        __syncthreads();
        for (int i = start + t; i < end; i += 256) {
            const float l0 = logits[(size_t)(N_POSA+i)*2+0];
            const float l1 = logits[(size_t)(N_POSA+i)*2+1];
            const unsigned int bits = monobits(l0 - l1);
            const unsigned int bin = bits >> (32-HBITS_A);
            if (bin <= selv) {
                const unsigned int sh  = (bin & 1) << 4;
                const unsigned int old = atomicAdd(&lh[bin >> 1], 1u << sh);
                const unsigned int pos = (old >> sh) & 0xFFFFu;
                A[pos] = ((unsigned long long)bits << 32) | (unsigned)i;
            }
        }
        return;
    }
    {
        const int sp = sbid - 65;
        unsigned short* b1   = (unsigned short*)smraw;           // 4096 ushort
        unsigned short* b2   = (unsigned short*)(smraw + 8192);  // 4096 ushort
        unsigned int*   temp = (unsigned int*)(smraw + 16384);   // 256 u32
        unsigned int s = 0;
        for (int k = 0; k < 16; ++k) s += histP1[t*16 + k];
        temp[t] = s;
        __syncthreads();
        for (int off = 1; off < 256; off <<= 1) {
            const unsigned int v = (t >= off) ? temp[t-off] : 0u;
            __syncthreads(); temp[t] += v; __syncthreads();
        }
        unsigned int run = (t == 0) ? 0u : temp[t-1];
        for (int k = 0; k < 16; ++k) {
            const int b = t*16 + k;
            b1[b] = (unsigned short)run;
            run += histP1[b];
        }
        __syncthreads();
        s = 0;
        for (int k = 0; k < 16; ++k) s += histP2[t*16 + k];
        temp[t] = s;
        __syncthreads();
        for (int off = 1; off < 256; off <<= 1) {
            const unsigned int v = (t >= off) ? temp[t-off] : 0u;
            __syncthreads(); temp[t] += v; __syncthreads();
        }
        run = (t == 0) ? 0u : temp[t-1];
        for (int k = 0; k < 16; ++k) {
            const int b = t*16 + k;
            b2[b] = (unsigned short)run;
            run += histP2[b];
        }
        __syncthreads();
        const int i = sp*256 + t;
        if (i < POOLN) {
            const unsigned long long k1 = T1[i];
            const unsigned int bn1 = (unsigned)(k1 >> 52);
            const unsigned int p1 = (unsigned)b1[bn1] + atomicAdd(&resvP1[bn1], 1u);
            P1[p1] = k1;
            const unsigned long long k2 = T2[i];
            const unsigned int bn2 = (unsigned)(k2 >> 52);
            const unsigned int p2 = (unsigned)b2[bn2] + atomicAdd(&resvP2[bn2], 1u);
            P2[p2] = k2;
        }
    }
}

// ---------------------------------------------------------------------------
// k_stageC: blocks [0,nslots): roi over listLo (lvl 0).
//           blocks [nslots, nslots+512): rankA (256-thread counting-sort).
//           blocks [nslots+512, nslots+512+157): rankP (thread-per-element).
// ---------------------------------------------------------------------------
__global__ __launch_bounds__(256) void k_stageC(
    const __hip_bfloat16* __restrict__ tl, const float* __restrict__ rois,
    float* __restrict__ out,
    const unsigned long long* __restrict__ A,
    const unsigned long long* __restrict__ P1, const unsigned long long* __restrict__ P2,
    const unsigned int* __restrict__ baseA,
    const unsigned int* __restrict__ baseP1, const unsigned int* __restrict__ baseP2,
    const unsigned int* __restrict__ sel,
    unsigned int* __restrict__ As, unsigned int* __restrict__ P1s,
    unsigned int* __restrict__ P2s,
    const unsigned int* __restrict__ listLo, const unsigned int* __restrict__ cnt,
    int nslots)
{
    __shared__ __align__(16) unsigned char smraw[32768];
    const int bid = blockIdx.x;
    const int t   = threadIdx.x;
    if (bid < nslots) {
        if ((unsigned)bid < cnt[1]) do_roi((int)listLo[bid], tl, rois, out, smraw);
        return;
    }
    const int sbid = bid - nslots;
    if (sbid < NRANKA) {
        unsigned int*   gkey = (unsigned int*)smraw;
        unsigned short* gsub = (unsigned short*)(smraw + 16384);
        unsigned int*   h2p  = (unsigned int*)(smraw + 24576);
        unsigned int*   st   = (unsigned int*)(smraw + 16384);
        const unsigned int selv = sel[0];
        for (unsigned int bin = (unsigned)sbid; bin <= selv; bin += NRANKA) {
            const int base = (int)baseA[bin];
            const int cnt_ = (int)baseA[bin+1] - base;
            if (cnt_ <= 0) continue;
            if (cnt_ == 1) {
                if (t == 0) As[base] = (unsigned)(A[base] & 0xffffffffu);
                continue;
            }
            if (cnt_ <= SUBN) {
                for (int b = t; b < SUBN/2; b += 256) h2p[b] = 0u;
                __syncthreads();
                for (int k = t; k < cnt_; k += 256) {
                    const unsigned int sub =
                        ((unsigned)(A[base+k] >> 32) >> 7) & (SUBN-1);
                    atomicAdd(&h2p[sub >> 1], 1u << ((sub & 1) << 4));
                }
                __syncthreads();
                unsigned int tmp[8];
                unsigned int s = 0;
                for (int w = 0; w < 8; ++w) {
                    const unsigned int v = h2p[t*8 + w];
                    tmp[w] = v;
                    s += (v & 0xFFFFu) + (v >> 16);
                }
                st[t] = s;
                __syncthreads();
                for (int off = 1; off < 256; off <<= 1) {
                    const unsigned int v = (t >= off) ? st[t-off] : 0u;
                    __syncthreads();
                    st[t] += v;
                    __syncthreads();
                }
                unsigned int run = (t == 0) ? 0u : st[t-1];
                __syncthreads();
                for (int w = 0; w < 8; ++w) {
                    const unsigned int v = tmp[w];
                    const unsigned int lo = run; run += (v & 0xFFFFu);
                    const unsigned int hi = run; run += (v >> 16);
                    h2p[t*8 + w] = lo | (hi << 16);
                }
                __syncthreads();
                for (int k = t; k < cnt_; k += 256) {
                    const unsigned long long key = A[base+k];
                    const unsigned int bits = (unsigned)(key >> 32);
                    const unsigned int sub  = (bits >> 7) & (SUBN-1);
                    const unsigned int sh   = (sub & 1) << 4;
                    const unsigned int old  = atomicAdd(&h2p[sub >> 1], 1u << sh);
                    const unsigned int pos  = (old >> sh) & 0xFFFFu;
                    gkey[pos] = ((bits & 0x7Fu) << 18) | (unsigned)(key & 0xffffffffu);
                    gsub[pos] = (unsigned short)sub;
                }
                __syncthreads();
                for (int p = t; p < cnt_; p += 256) {
                    const unsigned int k25 = gkey[p];
                    const unsigned short sb = gsub[p];
                    int b0 = p; while (b0 > 0 && gsub[b0-1] == sb) --b0;
                    int e0 = p; while (e0+1 < cnt_ && gsub[e0+1] == sb) ++e0;
                    int r = b0;
                    for (int q = b0; q <= e0; ++q) r += (gkey[q] < k25) ? 1 : 0;
                    As[base + r] = k25 & 0x3FFFFu;
                }
                __syncthreads();
            } else {
                for (int k = t; k < cnt_; k += 256) {
                    const unsigned long long key = A[base+k];
                    int rank = 0;
                    for (int j = 0; j < cnt_; ++j) rank += (A[base+j] < key) ? 1 : 0;
                    As[base + rank] = (unsigned)(key & 0xffffffffu);
                }
            }
        }
        return;
    }
    const int g = (sbid - NRANKA)*256 + t;
    if (g < POOLN) {
        const unsigned long long key = P1[g];
        const unsigned int bin = (unsigned)(key >> 52);
        const int b0 = (int)baseP1[bin], b1 = (int)baseP1[bin+1];
        int rank = 0;
        for (int j = b0; j < b1; ++j) rank += (P1[j] < key) ? 1 : 0;
        P1s[b0 + rank] = (unsigned)(key & 0xffffffffu);
    } else if (g < 2*POOLN) {
        const int e = g - POOLN;
        const unsigned long long key = P2[e];
        const unsigned int bin = (unsigned)(key >> 52);
        const int b0 = (int)baseP2[bin], b1 = (int)baseP2[bin+1];
        int rank = 0;
        for (int j = b0; j < b1; ++j) rank += (P2[j] < key) ? 1 : 0;
        P2s[b0 + rank] = (unsigned)(key & 0xffffffffu);
    }
}

// ---------------------------------------------------------------------------
// Fallback ROI align (NCHW direct), used if ws too small for transpose.
// ---------------------------------------------------------------------------
__global__ __launch_bounds__(256) void k_roi(
    const float* __restrict__ f0, const float* __restrict__ f1,
    const float* __restrict__ f2, const float* __restrict__ f3,
    const float* __restrict__ rois, float* __restrict__ out)
{
    __shared__ int   s_a[NBINS][4];
    __shared__ float s_w[NBINS][4];
    const int n   = blockIdx.x;
    const int tid = threadIdx.x;

    const float ry1 = rois[n*5+0], rx1 = rois[n*5+1];
    const float ry2 = rois[n*5+2], rx2 = rois[n*5+3];
    const int   b   = (int)rois[n*5+4];
    const int lvl = roi_level(rois, n);
    const int H = 256 >> lvl;
    const float* f = (lvl==0) ? f0 : (lvl==1) ? f1 : (lvl==2) ? f2 : f3;

    const float Hf  = (float)H;
    const float y1p = ry1*Hf, x1p = rx1*Hf, y2p = ry2*Hf, x2p = rx2*Hf;
    const float bh = (y2p - y1p) / 7.0f, bw = (x2p - x1p) / 7.0f;

    if (tid < NBINS) {
        const int py = tid / 7, px = tid % 7;
        float sy = y1p + bh*((float)py + 0.5f);
        float sx = x1p + bw*((float)px + 0.5f);
        sy = fminf(fmaxf(sy, 0.0f), Hf - 1.0f);
        sx = fminf(fmaxf(sx, 0.0f), Hf - 1.0f);
        const float y0f = floorf(sy), x0f = floorf(sx);
        const int y0 = (int)y0f, x0 = (int)x0f;
        const int y1i = min(y0+1, H-1), x1i = min(x0+1, H-1);
        const float wy = sy - y0f, wx = sx - x0f;
        s_a[tid][0] = y0 *H + x0;
        s_a[tid][1] = y0 *H + x1i;
        s_a[tid][2] = y1i*H + x0;
        s_a[tid][3] = y1i*H + x1i;
        const float omy = 1.0f - wy, omx = 1.0f - wx;
        s_w[tid][0] = omy*omx; s_w[tid][1] = omy*wx;
        s_w[tid][2] = wy *omx; s_w[tid][3] = wy *wx;
    }
    __syncthreads();

    const int hw = H*H;
    const float* basep = f + (size_t)b * NCH * hw;
    float* outn = out + (size_t)n * (NCH*NBINS);
    for (int t = tid; t < NCH*NBINS; t += 256) {
        const int c   = t / NBINS;
        const int bin = t - c*NBINS;
        const float* p = basep + (size_t)c * hw;
        outn[t] = p[s_a[bin][0]]*s_w[bin][0] + p[s_a[bin][1]]*s_w[bin][1]
                + p[s_a[bin][2]]*s_w[bin][2] + p[s_a[bin][3]]*s_w[bin][3];
    }
}

// ---------------------------------------------------------------------------
__global__ __launch_bounds__(256) void k_final(
    const float* __restrict__ logits, const unsigned int* __restrict__ As,
    const unsigned int* __restrict__ P1s, const unsigned int* __restrict__ P2s,
    const float* __restrict__ partial, float* __restrict__ out2)
{
    __shared__ float red[256];
    const int t = threadIdx.x;
    float s = 0.0f;
    for (int j = t; j < N_POSA; j += 256) {
        const unsigned int i2 = P2s[j];
        const unsigned int r  = P1s[i2];
        const unsigned int i  = As[r];
        const float l0 = logits[(size_t)(N_POSA+i)*2+0];
        const float l1 = logits[(size_t)(N_POSA+i)*2+1];
        const float m = fmaxf(l0, l1);
        s += (l0 - m) - logf(expf(l0-m) + expf(l1-m));
    }
    red[t] = s;
    __syncthreads();
    for (int off = 128; off > 0; off >>= 1) {
        if (t < off) red[t] += red[t+off];
        __syncthreads();
    }
    if (t == 0) {
        const float neg_loss = -red[0] / (float)N_POSA;
        const float pos_loss = -partial[0] / (float)N_POSA;
        out2[0] = 0.5f * (pos_loss + neg_loss);
        out2[1] = partial[1] / (float)(N_POSA*4);
    }
}

// ---------------------------------------------------------------------------
extern "C" void kernel_launch(void* const* d_in, const int* in_sizes, int n_in,
                              void* d_out, int out_size, void* d_ws, size_t ws_size,
                              hipStream_t stream)
{
    const float* f0     = (const float*)d_in[0];
    const float* f1     = (const float*)d_in[1];
    const float* f2     = (const float*)d_in[2];
    const float* f3     = (const float*)d_in[3];
    const float* rois   = (const float*)d_in[4];
    const int*   am     = (const int*)  d_in[5];
    const float* logits = (const float*)d_in[6];
    const float* pd     = (const float*)d_in[7];
    const float* td     = (const float*)d_in[8];
    float* out = (float*)d_out;

    char* ws = (char*)d_ws;
    unsigned long long* A      = (unsigned long long*)(ws);            // 262144
    unsigned long long* T1     = (unsigned long long*)(ws +  262144); // 160000
    unsigned long long* T2     = (unsigned long long*)(ws +  422144); // 160000
    unsigned long long* P1     = (unsigned long long*)(ws +  582144); // 160000
    unsigned long long* P2     = (unsigned long long*)(ws +  742144); // 160000
    unsigned int*       histA  = (unsigned int*)      (ws +  902144); // 32768
    unsigned int*       histP1 = (unsigned int*)      (ws +  934912); // 16384
    unsigned int*       histP2 = (unsigned int*)      (ws +  951296); // 16384
    unsigned int*       baseA  = (unsigned int*)      (ws +  967680); // 32832
    unsigned int*       resvA  = (unsigned int*)      (ws + 1000512); // 32768
    unsigned int*       baseP1 = (unsigned int*)      (ws + 1033344); // 16448
    unsigned int*       resvP1 = (unsigned int*)      (ws + 1049792); // 16384
    unsigned int*       baseP2 = (unsigned int*)      (ws + 1066240); // 16448
    unsigned int*       resvP2 = (unsigned int*)      (ws + 1082688); // 16384
    unsigned int*       sel    = (unsigned int*)      (ws + 1099136); // 64
    float*              prt    = (float*)             (ws + 1099200); // 64
    unsigned int*       listHi = (unsigned int*)      (ws + 1099264); // 16000
    unsigned int*       listLo = (unsigned int*)      (ws + 1115264); // 16000
    unsigned int*       cnt    = (unsigned int*)      (ws + 1131264); // 64
    __hip_bfloat16*     tl     = (__hip_bfloat16*)    (ws + 1131328); // 44564480
    unsigned int*       As     = (unsigned int*)T1;
    unsigned int*       P1s    = (unsigned int*)T2;
    unsigned int*       P2s    = (unsigned int*)((char*)T2 + 80000);
    const size_t NEED = 1131328ull + TLELEMS * 2ull;
    const bool use_cl = (ws_size >= NEED);

    // 1) zero hists + reservation counters + bucket counts
    k_zero<<<128, 256, 0, stream>>>(histA, resvA, resvP1, resvP2, cnt);

    // 2) A: transpose L1-3 || prep || bucket
    k_stageA<<<(use_cl ? NTRA : 0) + NPREP, 256, 0, stream>>>(
        f0, f1, f2, f3, tl, rois, T1, T2, histA, histP1, histP2,
        am, logits, pd, td, prt, listHi, listLo, cnt, use_cl ? NTRA : 0);

    if (!use_cl)
        k_roi<<<NROIS, 256, 0, stream>>>(f0, f1, f2, f3, rois, out);

    // 3) B: transpose L0 || roi(lvl>=1) || scan || scatter
    {
        const int ntrB   = use_cl ? NTRB : 0;
        const int nslots = use_cl ? NROIS : 0;
        k_stageB<<<ntrB + nslots + 144, 256, 0, stream>>>(
            f0, f1, f2, f3, tl, rois, out, logits, T1, T2, A, P1, P2,
            histA, histP1, histP2, baseA, baseP1, baseP2,
            resvA, resvP1, resvP2, sel, listHi, cnt, ntrB, nslots);
    }

    // 4) C: roi(lvl0) || rankA || rankP
    {
        const int nslots = use_cl ? NROIS : 0;
        k_stageC<<<nslots + NRANKA + NRANKP, 256, 0, stream>>>(
            tl, rois, out, A, P1, P2, baseA, baseP1, baseP2, sel,
            As, P1s, P2s, listLo, cnt, nslots);
    }

    // 5) final scalars
    k_final<<<1, 256, 0, stream>>>(logits, As, P1s, P2s, prt,
                                   out + (size_t)NROIS*NCH*NBINS);
}

// Round 15
// 97.672 us; speedup vs baseline: 1.7773x; 1.7773x over previous
//
#include <hip/hip_runtime.h>
#include <hip/hip_bf16.h>
#include <cstdint>

#define NROIS  4000
#define NCH    128
#define NBINS  49
#define N_POSA 1000
#define N_NEGA 200000
#define POOLN  20000
#define HBITS_A 13
#define ABINS  8192
#define PBINS  4096
#define SUBN   4096
#define NTRBLK 2720
#define NPREP  106
#define NRANKA 512
#define NRANKP 40
#define TPAD   136

// tl (channels-last bf16 fmaps) element offsets per level
#define L0OFF 0ull
#define L1OFF 16777216ull
#define L2OFF 20971520ull
#define L3OFF 22020096ull
#define TLELEMS 22282240ull

// ---------------------------------------------------------------------------
// threefry2x32 (device) — exact JAX semantics
// ---------------------------------------------------------------------------
__device__ __forceinline__ uint32_t rotl32d(uint32_t v, int r) { return (v << r) | (v >> (32-r)); }

__device__ void tf2x32(uint32_t k0, uint32_t k1, uint32_t& x0, uint32_t& x1)
{
    const uint32_t ks2 = k0 ^ k1 ^ 0x1BD11BDAu;
    const int R0[4] = {13,15,26,6};
    const int R1[4] = {17,29,16,24};
    x0 += k0; x1 += k1;
#pragma unroll
    for (int r = 0; r < 4; ++r) { x0 += x1; x1 = rotl32d(x1, R0[r]); x1 ^= x0; }
    x0 += k1;  x1 += ks2 + 1u;
#pragma unroll
    for (int r = 0; r < 4; ++r) { x0 += x1; x1 = rotl32d(x1, R1[r]); x1 ^= x0; }
    x0 += ks2; x1 += k0 + 2u;
#pragma unroll
    for (int r = 0; r < 4; ++r) { x0 += x1; x1 = rotl32d(x1, R0[r]); x1 ^= x0; }
    x0 += k0;  x1 += k1 + 3u;
#pragma unroll
    for (int r = 0; r < 4; ++r) { x0 += x1; x1 = rotl32d(x1, R1[r]); x1 ^= x0; }
    x0 += k1;  x1 += ks2 + 4u;
#pragma unroll
    for (int r = 0; r < 4; ++r) { x0 += x1; x1 = rotl32d(x1, R0[r]); x1 ^= x0; }
    x0 += ks2; x1 += k0 + 5u;
}

__device__ __forceinline__ unsigned int monobits(float x) {
    unsigned int u = __float_as_uint(x);
    return (u & 0x80000000u) ? ~u : (u | 0x80000000u);
}

__device__ __forceinline__ unsigned short f2bf(float x) {
    union { __hip_bfloat16 h; unsigned short u; } c;
    c.h = __float2bfloat16(x);
    return c.u;
}

// ---------------------------------------------------------------------------
// k_zero: zero hists (16384 u32) + resvA (8192) + resvP1/P2 (4096 each).
// ---------------------------------------------------------------------------
__global__ void k_zero(unsigned int* __restrict__ h, unsigned int* __restrict__ rA,
                       unsigned int* __restrict__ rP1, unsigned int* __restrict__ rP2)
{
    const int b = blockIdx.x;
    const int i = b*256 + threadIdx.x;
    if      (b <  64) h[i] = 0u;
    else if (b <  96) rA[i - 64*256] = 0u;
    else if (b < 112) rP1[i - 96*256] = 0u;
    else              rP2[i - 112*256] = 0u;
}

// ---------------------------------------------------------------------------
// k_trprep: blocks [0,ntr): NCHW->NHWC f32->bf16 transpose, 64hw x 128ch tile.
//           blocks [ntr, ntr+106): prep (perm keys+hists, OHEM hist, losses).
// ---------------------------------------------------------------------------
__global__ __launch_bounds__(256) void k_trprep(
    const float* __restrict__ f0, const float* __restrict__ f1,
    const float* __restrict__ f2, const float* __restrict__ f3,
    __hip_bfloat16* __restrict__ tl,
    unsigned long long* __restrict__ T1, unsigned long long* __restrict__ T2,
    unsigned int* __restrict__ histA,
    unsigned int* __restrict__ histP1, unsigned int* __restrict__ histP2,
    const int* __restrict__ am, const float* __restrict__ logits,
    const float* __restrict__ pd, const float* __restrict__ td,
    float* __restrict__ prt, int ntr)
{
    __shared__ __align__(16) unsigned char smraw[32768];
    const int bid = blockIdx.x;
    const int t   = threadIdx.x;

    if (bid < ntr) {
        unsigned short* s = (unsigned short*)smraw;   // [64][TPAD] bf16, swizzled
        const int bz = bid / 1360;
        const int r  = bid - bz*1360;
        int lvl, tile;
        if      (r < 1024) { lvl = 0; tile = r; }
        else if (r < 1280) { lvl = 1; tile = r - 1024; }
        else if (r < 1344) { lvl = 2; tile = r - 1280; }
        else               { lvl = 3; tile = r - 1344; }
        const int HW = 65536 >> (2*lvl);
        const float* in = (lvl==0) ? f0 : (lvl==1) ? f1 : (lvl==2) ? f2 : f3;
        const size_t ooff = (lvl==0) ? L0OFF : (lvl==1) ? L1OFF : (lvl==2) ? L2OFF : L3OFF;
        const int hw0 = tile * 64;
        const float4* in4 = (const float4*)(in + (size_t)bz * 128 * HW);
        const int HW4 = HW >> 2;
        const int h4b = hw0 >> 2;
#pragma unroll
        for (int k = 0; k < 8; ++k) {
            const int idx = t + k*256;
            const int c   = idx >> 4;
            const int h4  = idx & 15;
            const float4 v = in4[(size_t)c * HW4 + h4b + h4];
            const int r0 = h4 * 4;
            const int cs = c ^ ((h4 & 7) << 3);
            s[(r0+0)*TPAD + cs] = f2bf(v.x);
            s[(r0+1)*TPAD + cs] = f2bf(v.y);
            s[(r0+2)*TPAD + cs] = f2bf(v.z);
            s[(r0+3)*TPAD + cs] = f2bf(v.w);
        }
        __syncthreads();
        uint4* out4 = (uint4*)(tl + ooff + (size_t)bz * (size_t)HW * 128
                                         + (size_t)hw0 * 128);
        const int rr = t >> 4;
        const int q  = t & 15;
        const int c8 = q * 8;
#pragma unroll
        for (int m = 0; m < 4; ++m) {
            const int row = rr + m*16;
            const int sw = ((row >> 2) & 7) << 3;
            out4[row*16 + q] = *(const uint4*)&s[row*TPAD + (c8 ^ sw)];
        }
        return;
    }

    const int pbid = bid - ntr;
    if (pbid < 40) {
        unsigned int* buf = (unsigned int*)smraw;
        unsigned int* lh1 = buf;
        unsigned int* lh2 = buf + PBINS;
        for (int b = t; b < 2*PBINS; b += 256) buf[b] = 0u;
        __syncthreads();
        const int i = pbid*256 + t;
        if (i < POOLN/2) {
            uint32_t a0 = 0u, a1 = 2u; tf2x32(0u, 1u, a0, a1);
            uint32_t b0 = 1u, b1 = 3u; tf2x32(0u, 1u, b0, b1);
            uint32_t c0 = 0u, c1 = 2u; tf2x32(a0, b0, c0, c1);
            uint32_t d0 = 1u, d1 = 3u; tf2x32(a0, b0, d0, d1);
            uint32_t x0 = (uint32_t)i, x1 = (uint32_t)(POOLN/2 + i);
            tf2x32(a1, b1, x0, x1);
            T1[i]           = ((unsigned long long)x0 << 32) | (unsigned)i;
            T1[POOLN/2 + i] = ((unsigned long long)x1 << 32) | (unsigned)(POOLN/2 + i);
            atomicAdd(&lh1[x0 >> 20], 1u);
            atomicAdd(&lh1[x1 >> 20], 1u);
            uint32_t y0 = (uint32_t)i, y1 = (uint32_t)(POOLN/2 + i);
            tf2x32(c1, d1, y0, y1);
            T2[i]           = ((unsigned long long)y0 << 32) | (unsigned)i;
            T2[POOLN/2 + i] = ((unsigned long long)y1 << 32) | (unsigned)(POOLN/2 + i);
            atomicAdd(&lh2[y0 >> 20], 1u);
            atomicAdd(&lh2[y1 >> 20], 1u);
        }
        __syncthreads();
        for (int b = t; b < PBINS; b += 256) {
            unsigned int v = lh1[b]; if (v) atomicAdd(&histP1[b], v);
            v = lh2[b];              if (v) atomicAdd(&histP2[b], v);
        }
        return;
    }
    if (pbid < 104) {
        unsigned int* buf = (unsigned int*)smraw;
        for (int b = t; b < ABINS; b += 256) buf[b] = 0u;
        __syncthreads();
        for (int i = (pbid-40)*256 + t; i < N_NEGA; i += 64*256) {
            const float l0 = logits[(size_t)(N_POSA+i)*2+0];
            const float l1 = logits[(size_t)(N_POSA+i)*2+1];
            atomicAdd(&buf[monobits(l0 - l1) >> (32-HBITS_A)], 1u);
        }
        __syncthreads();
        for (int b = t; b < ABINS; b += 256) {
            const unsigned int v = buf[b];
            if (v) atomicAdd(&histA[b], v);
        }
        return;
    }
    float* red = (float*)smraw;
    float s = 0.0f;
    if (pbid == 104) {
        for (int i = t; i < N_POSA; i += 256) {
            const int tgt = am[i];
            const float l0 = logits[(size_t)i*2+0], l1 = logits[(size_t)i*2+1];
            const float m = fmaxf(l0, l1);
            const float lse = logf(expf(l0-m) + expf(l1-m));
            const float lt = (tgt == 0) ? l0 : l1;
            s += (lt - m) - lse;
        }
    } else {
        for (int i = t; i < N_POSA*4; i += 256) {
            const float d = fabsf(pd[i] - td[i]);
            s += (d < 1.0f) ? 0.5f*d*d : d - 0.5f;
        }
    }
    red[t] = s;
    __syncthreads();
    for (int off = 128; off > 0; off >>= 1) {
        if (t < off) red[t] += red[t+off];
        __syncthreads();
    }
    if (t == 0) prt[pbid - 104] = red[0];
}

// ---------------------------------------------------------------------------
// 256-thread exclusive scan helper (hist -> base only)
// ---------------------------------------------------------------------------
__device__ void scan_one256(const unsigned int* __restrict__ hist,
                            unsigned int* __restrict__ base, int n, unsigned int* lds)
{
    const int t = threadIdx.x;
    const int chunk = n >> 8;
    unsigned int s = 0;
    for (int k = 0; k < chunk; ++k) s += hist[t*chunk + k];
    lds[t] = s;
    __syncthreads();
    for (int off = 1; off < 256; off <<= 1) {
        unsigned int v = (t >= off) ? lds[t-off] : 0u;
        __syncthreads();
        lds[t] += v;
        __syncthreads();
    }
    unsigned int run = (t == 0) ? 0u : lds[t-1];
    for (int k = 0; k < chunk; ++k) {
        base[t*chunk+k] = run;
        run += hist[t*chunk+k];
    }
    if (t == 255) base[n] = run;
    __syncthreads();
}

// ---------------------------------------------------------------------------
// roi device fn: half-channel staging (12.5 KB s_o) + uint4 taps.
// smraw usage: 784 + 784 + 12544 = 14112 B.
// ---------------------------------------------------------------------------
__device__ void do_roi(int n, const __hip_bfloat16* __restrict__ tl,
                       const float* __restrict__ rois, float* __restrict__ out,
                       unsigned char* smraw)
{
    int   (*s_a)[4] = (int(*)[4])smraw;
    float (*s_w)[4] = (float(*)[4])(smraw + 784);
    float* s_o      = (float*)(smraw + 1568);          // 64*49 floats
    const int tid = threadIdx.x;

    const float ry1 = rois[n*5+0], rx1 = rois[n*5+1];
    const float ry2 = rois[n*5+2], rx2 = rois[n*5+3];
    const int   b   = (int)rois[n*5+4];
    const float h = ry2 - ry1, w = rx2 - rx1;
    const float lraw = rintf(4.0f + log2f(sqrtf(h*w + 1e-12f)));
    int lvl = (int)lraw; lvl = lvl < 0 ? 0 : (lvl > 3 ? 3 : lvl);
    const int H = 256 >> lvl;
    const size_t lbase = (lvl==0) ? L0OFF : (lvl==1) ? L1OFF : (lvl==2) ? L2OFF : L3OFF;
    const __hip_bfloat16* bp = tl + lbase + (size_t)b * (size_t)(H*H) * NCH;

    const float Hf  = (float)H;
    const float y1p = ry1*Hf, x1p = rx1*Hf, y2p = ry2*Hf, x2p = rx2*Hf;
    const float bh = (y2p - y1p) / 7.0f, bw = (x2p - x1p) / 7.0f;

    if (tid < NBINS) {
        const int py = tid / 7, px = tid % 7;
        float sy = y1p + bh*((float)py + 0.5f);
        float sx = x1p + bw*((float)px + 0.5f);
        sy = fminf(fmaxf(sy, 0.0f), Hf - 1.0f);
        sx = fminf(fmaxf(sx, 0.0f), Hf - 1.0f);
        const float y0f = floorf(sy), x0f = floorf(sx);
        const int y0 = (int)y0f, x0 = (int)x0f;
        const int y1i = min(y0+1, H-1), x1i = min(x0+1, H-1);
        const float wy = sy - y0f, wx = sx - x0f;
        s_a[tid][0] = y0 *H + x0;
        s_a[tid][1] = y0 *H + x1i;
        s_a[tid][2] = y1i*H + x0;
        s_a[tid][3] = y1i*H + x1i;
        const float omy = 1.0f - wy, omx = 1.0f - wx;
        s_w[tid][0] = omy*omx; s_w[tid][1] = omy*wx;
        s_w[tid][2] = wy *omx; s_w[tid][3] = wy *wx;
    }
    __syncthreads();

    const int c8 = tid & 7;           // 8-ch group within 64-ch half
    const int bg = tid >> 3;          // 0..31
#pragma unroll
    for (int half = 0; half < 2; ++half) {
        if (half) __syncthreads();    // s_o reuse
        for (int bin = bg; bin < NBINS; bin += 32) {
            float a0=0.f,a1=0.f,a2=0.f,a3=0.f,a4=0.f,a5=0.f,a6=0.f,a7=0.f;
#pragma unroll
            for (int tap = 0; tap < 4; ++tap) {
                const uint4 v = *(const uint4*)
                    (bp + (size_t)s_a[bin][tap]*NCH + half*64 + 8*c8);
                const float wgt = s_w[bin][tap];
                a0 += __uint_as_float(v.x << 16)         * wgt;
                a1 += __uint_as_float(v.x & 0xffff0000u) * wgt;
                a2 += __uint_as_float(v.y << 16)         * wgt;
                a3 += __uint_as_float(v.y & 0xffff0000u) * wgt;
                a4 += __uint_as_float(v.z << 16)         * wgt;
                a5 += __uint_as_float(v.z & 0xffff0000u) * wgt;
                a6 += __uint_as_float(v.w << 16)         * wgt;
                a7 += __uint_as_float(v.w & 0xffff0000u) * wgt;
            }
            s_o[(8*c8+0)*NBINS + bin] = a0;
            s_o[(8*c8+1)*NBINS + bin] = a1;
            s_o[(8*c8+2)*NBINS + bin] = a2;
            s_o[(8*c8+3)*NBINS + bin] = a3;
            s_o[(8*c8+4)*NBINS + bin] = a4;
            s_o[(8*c8+5)*NBINS + bin] = a5;
            s_o[(8*c8+6)*NBINS + bin] = a6;
            s_o[(8*c8+7)*NBINS + bin] = a7;
        }
        __syncthreads();
        float4* outn = (float4*)(out + (size_t)n*(NCH*NBINS) + half*64*NBINS);
        const float4* so4 = (const float4*)s_o;
        for (int t4 = tid; t4 < (64*NBINS)/4; t4 += 256)
            outn[t4] = so4[t4];
    }
}

// ---------------------------------------------------------------------------
// k_stage3: blocks [0,rcnt): roi. block rcnt: scans+sel. blocks rcnt+1..rcnt+64:
// A-scatter (self-derived bases). blocks rcnt+65..rcnt+143: P-scatter.
// smraw = 17440 B -> 8 blocks/CU (thread-capped), full wave occupancy.
// ---------------------------------------------------------------------------
__global__ __launch_bounds__(256, 8) void k_stage3(
    const __hip_bfloat16* __restrict__ tl, const float* __restrict__ rois,
    float* __restrict__ out, const float* __restrict__ logits,
    const unsigned long long* __restrict__ T1, const unsigned long long* __restrict__ T2,
    unsigned long long* __restrict__ A,
    unsigned long long* __restrict__ P1, unsigned long long* __restrict__ P2,
    const unsigned int* __restrict__ histA,
    const unsigned int* __restrict__ histP1, const unsigned int* __restrict__ histP2,
    unsigned int* __restrict__ baseA, unsigned int* __restrict__ baseP1,
    unsigned int* __restrict__ baseP2,
    unsigned int* __restrict__ resvA, unsigned int* __restrict__ resvP1,
    unsigned int* __restrict__ resvP2,
    unsigned int* __restrict__ sel, int rcnt)
{
    __shared__ __align__(16) unsigned char smraw[17440];
    const int bid = blockIdx.x;
    const int t   = threadIdx.x;
    if (bid < rcnt) { do_roi(bid, tl, rois, out, smraw); return; }

    const int sbid = bid - rcnt;
    if (sbid == 0) {
        unsigned int* lds = (unsigned int*)smraw;
        scan_one256(histA, baseA, ABINS, lds);
        scan_one256(histP1, baseP1, PBINS, lds);
        scan_one256(histP2, baseP2, PBINS, lds);
        const int chunk = ABINS >> 8;
        for (int k = 0; k < chunk; ++k) {
            const int bin = t*chunk + k;
            if (baseA[bin] < POOLN && baseA[bin] + histA[bin] >= POOLN)
                sel[0] = (unsigned int)bin;
        }
        return;
    }
    if (sbid <= 64) {
        const int sa = sbid - 1;
        unsigned int* lh   = (unsigned int*)smraw;            // 4096 u32 packed
        unsigned int* temp = (unsigned int*)(smraw + 16384);  // 256 u32
        unsigned int* svl  = (unsigned int*)(smraw + 17408);  // 1 u32
        for (int b = t; b < ABINS/2; b += 256) lh[b] = 0u;
        unsigned int s = 0;
        for (int k = 0; k < 32; ++k) s += histA[t*32 + k];
        temp[t] = s;
        __syncthreads();
        for (int off = 1; off < 256; off <<= 1) {
            const unsigned int v = (t >= off) ? temp[t-off] : 0u;
            __syncthreads();
            temp[t] += v;
            __syncthreads();
        }
        unsigned int run = (t == 0) ? 0u : temp[t-1];
        for (int k = 0; k < 32; ++k) {
            const int b = t*32 + k;
            const unsigned int hv = histA[b];
            if (run < POOLN && run + hv >= POOLN) svl[0] = (unsigned int)b;
            run += hv;
        }
        __syncthreads();
        const unsigned int selv = svl[0];
        const int start = sa * (N_NEGA/64);
        const int end   = start + (N_NEGA/64);
        for (int i = start + t; i < end; i += 256) {
            const float l0 = logits[(size_t)(N_POSA+i)*2+0];
            const float l1 = logits[(size_t)(N_POSA+i)*2+1];
            const unsigned int bin = monobits(l0 - l1) >> (32-HBITS_A);
            if (bin <= selv) atomicAdd(&lh[bin >> 1], 1u << ((bin & 1) << 4));
        }
        __syncthreads();
        run = (t == 0) ? 0u : temp[t-1];
        for (int k = 0; k < 32; k += 2) {
            const int b0 = t*32 + k;
            const unsigned int packed = lh[b0 >> 1];
            const unsigned int c0 = packed & 0xFFFFu, c1 = packed >> 16;
            unsigned int n0 = 0u, n1 = 0u;
            if (c0) n0 = run + atomicAdd(&resvA[b0], c0);
            run += histA[b0];
            if (c1) n1 = run + atomicAdd(&resvA[b0+1], c1);
            run += histA[b0+1];
            lh[b0 >> 1] = n0 | (n1 << 16);
        }
        __syncthreads();
        for (int i = start + t; i < end; i += 256) {
            const float l0 = logits[(size_t)(N_POSA+i)*2+0];
            const float l1 = logits[(size_t)(N_POSA+i)*2+1];
            const unsigned int bits = monobits(l0 - l1);
            const unsigned int bin = bits >> (32-HBITS_A);
            if (bin <= selv) {
                const unsigned int sh  = (bin & 1) << 4;
                const unsigned int old = atomicAdd(&lh[bin >> 1], 1u << sh);
                const unsigned int pos = (old >> sh) & 0xFFFFu;
                A[pos] = ((unsigned long long)bits << 32) | (unsigned)i;
            }
        }
        return;
    }
    {
        const int sp = sbid - 65;
        unsigned short* b1   = (unsigned short*)smraw;           // 4096 ushort
        unsigned short* b2   = (unsigned short*)(smraw + 8192);  // 4096 ushort
        unsigned int*   temp = (unsigned int*)(smraw + 16384);   // 256 u32
        unsigned int s = 0;
        for (int k = 0; k < 16; ++k) s += histP1[t*16 + k];
        temp[t] = s;
        __syncthreads();
        for (int off = 1; off < 256; off <<= 1) {
            const unsigned int v = (t >= off) ? temp[t-off] : 0u;
            __syncthreads(); temp[t] += v; __syncthreads();
        }
        unsigned int run = (t == 0) ? 0u : temp[t-1];
        for (int k = 0; k < 16; ++k) {
            const int b = t*16 + k;
            b1[b] = (unsigned short)run;
            run += histP1[b];
        }
        __syncthreads();
        s = 0;
        for (int k = 0; k < 16; ++k) s += histP2[t*16 + k];
        temp[t] = s;
        __syncthreads();
        for (int off = 1; off < 256; off <<= 1) {
            const unsigned int v = (t >= off) ? temp[t-off] : 0u;
            __syncthreads(); temp[t] += v; __syncthreads();
        }
        run = (t == 0) ? 0u : temp[t-1];
        for (int k = 0; k < 16; ++k) {
            const int b = t*16 + k;
            b2[b] = (unsigned short)run;
            run += histP2[b];
        }
        __syncthreads();
        const int i = sp*256 + t;
        if (i < POOLN) {
            const unsigned long long k1 = T1[i];
            const unsigned int bn1 = (unsigned)(k1 >> 52);
            const unsigned int p1 = (unsigned)b1[bn1] + atomicAdd(&resvP1[bn1], 1u);
            P1[p1] = k1;
            const unsigned long long k2 = T2[i];
            const unsigned int bn2 = (unsigned)(k2 >> 52);
            const unsigned int p2 = (unsigned)b2[bn2] + atomicAdd(&resvP2[bn2], 1u);
            P2[p2] = k2;
        }
    }
}

// ---------------------------------------------------------------------------
// Fallback ROI align (NCHW direct), used if ws too small for transpose.
// ---------------------------------------------------------------------------
__global__ __launch_bounds__(256) void k_roi(
    const float* __restrict__ f0, const float* __restrict__ f1,
    const float* __restrict__ f2, const float* __restrict__ f3,
    const float* __restrict__ rois, float* __restrict__ out)
{
    __shared__ int   s_a[NBINS][4];
    __shared__ float s_w[NBINS][4];
    const int n   = blockIdx.x;
    const int tid = threadIdx.x;

    const float ry1 = rois[n*5+0], rx1 = rois[n*5+1];
    const float ry2 = rois[n*5+2], rx2 = rois[n*5+3];
    const int   b   = (int)rois[n*5+4];
    const float h = ry2 - ry1, w = rx2 - rx1;
    const float lraw = rintf(4.0f + log2f(sqrtf(h*w + 1e-12f)));
    int lvl = (int)lraw; lvl = lvl < 0 ? 0 : (lvl > 3 ? 3 : lvl);
    const int H = 256 >> lvl;
    const float* f = (lvl==0) ? f0 : (lvl==1) ? f1 : (lvl==2) ? f2 : f3;

    const float Hf  = (float)H;
    const float y1p = ry1*Hf, x1p = rx1*Hf, y2p = ry2*Hf, x2p = rx2*Hf;
    const float bh = (y2p - y1p) / 7.0f, bw = (x2p - x1p) / 7.0f;

    if (tid < NBINS) {
        const int py = tid / 7, px = tid % 7;
        float sy = y1p + bh*((float)py + 0.5f);
        float sx = x1p + bw*((float)px + 0.5f);
        sy = fminf(fmaxf(sy, 0.0f), Hf - 1.0f);
        sx = fminf(fmaxf(sx, 0.0f), Hf - 1.0f);
        const float y0f = floorf(sy), x0f = floorf(sx);
        const int y0 = (int)y0f, x0 = (int)x0f;
        const int y1i = min(y0+1, H-1), x1i = min(x0+1, H-1);
        const float wy = sy - y0f, wx = sx - x0f;
        s_a[tid][0] = y0 *H + x0;
        s_a[tid][1] = y0 *H + x1i;
        s_a[tid][2] = y1i*H + x0;
        s_a[tid][3] = y1i*H + x1i;
        const float omy = 1.0f - wy, omx = 1.0f - wx;
        s_w[tid][0] = omy*omx; s_w[tid][1] = omy*wx;
        s_w[tid][2] = wy *omx; s_w[tid][3] = wy *wx;
    }
    __syncthreads();

    const int hw = H*H;
    const float* basep = f + (size_t)b * NCH * hw;
    float* outn = out + (size_t)n * (NCH*NBINS);
    for (int t = tid; t < NCH*NBINS; t += 256) {
        const int c   = t / NBINS;
        const int bin = t - c*NBINS;
        const float* p = basep + (size_t)c * hw;
        outn[t] = p[s_a[bin][0]]*s_w[bin][0] + p[s_a[bin][1]]*s_w[bin][1]
                + p[s_a[bin][2]]*s_w[bin][2] + p[s_a[bin][3]]*s_w[bin][3];
    }
}

// ---------------------------------------------------------------------------
// k_rank: per-A-bin LDS counting-sort on the NEXT 12 key bits.
// ---------------------------------------------------------------------------
__global__ __launch_bounds__(1024) void k_rank(
    const unsigned long long* __restrict__ A,
    const unsigned long long* __restrict__ P1, const unsigned long long* __restrict__ P2,
    const unsigned int* __restrict__ baseA,
    const unsigned int* __restrict__ baseP1, const unsigned int* __restrict__ baseP2,
    const unsigned int* __restrict__ sel,
    unsigned int* __restrict__ As, unsigned int* __restrict__ P1s,
    unsigned int* __restrict__ P2s)
{
    __shared__ unsigned long long g[SUBN];
    __shared__ unsigned int h2[SUBN];
    __shared__ unsigned int h2b[SUBN];
    const int bid = blockIdx.x;
    const int t   = threadIdx.x;
    if (bid < NRANKA) {
        const unsigned int selv = sel[0];
        for (unsigned int bin = (unsigned)bid; bin <= selv; bin += NRANKA) {
            const int base = (int)baseA[bin];
            const int cnt  = (int)baseA[bin+1] - base;
            if (cnt <= 0) continue;
            if (cnt == 1) {
                if (t == 0) As[base] = (unsigned)(A[base] & 0xffffffffu);
                continue;
            }
            if (cnt <= SUBN) {
                for (int b = t; b < SUBN; b += 1024) h2[b] = 0u;
                __syncthreads();
                for (int k = t; k < cnt; k += 1024) {
                    const unsigned int sub = ((unsigned)(A[base+k] >> 32) >> 7) & (SUBN-1);
                    atomicAdd(&h2[sub], 1u);
                }
                __syncthreads();
                unsigned int c0 = h2[4*t+0], c1 = h2[4*t+1],
                             c2 = h2[4*t+2], c3 = h2[4*t+3];
                h2b[t] = c0 + c1 + c2 + c3;
                __syncthreads();
                for (int off = 1; off < 1024; off <<= 1) {
                    const unsigned int v = (t >= off) ? h2b[t-off] : 0u;
                    __syncthreads();
                    h2b[t] += v;
                    __syncthreads();
                }
                unsigned int run = (t == 0) ? 0u : h2b[t-1];
                __syncthreads();
                h2[4*t+0] = run; h2b[4*t+0] = run; run += c0;
                h2[4*t+1] = run; h2b[4*t+1] = run; run += c1;
                h2[4*t+2] = run; h2b[4*t+2] = run; run += c2;
                h2[4*t+3] = run; h2b[4*t+3] = run; run += c3;
                __syncthreads();
                for (int k = t; k < cnt; k += 1024) {
                    const unsigned long long key = A[base+k];
                    const unsigned int sub = ((unsigned)(key >> 32) >> 7) & (SUBN-1);
                    const unsigned int p = atomicAdd(&h2[sub], 1u);
                    g[p] = key;
                }
                __syncthreads();
                for (int p = t; p < cnt; p += 1024) {
                    const unsigned long long key = g[p];
                    const unsigned int sub = ((unsigned)(key >> 32) >> 7) & (SUBN-1);
                    const int b0 = (int)h2b[sub], e0 = (int)h2[sub];
                    int r = b0;
                    for (int q = b0; q < e0; ++q) r += (g[q] < key) ? 1 : 0;
                    As[base + r] = (unsigned)(key & 0xffffffffu);
                }
                __syncthreads();
            } else {
                for (int k = t; k < cnt; k += 1024) {
                    const unsigned long long key = A[base+k];
                    int rank = 0;
                    for (int j = 0; j < cnt; ++j) rank += (A[base+j] < key) ? 1 : 0;
                    As[base + rank] = (unsigned)(key & 0xffffffffu);
                }
            }
        }
        return;
    }
    const int gg = (bid - NRANKA)*1024 + t;
    if (gg < POOLN) {
        const unsigned long long key = P1[gg];
        const unsigned int bin = (unsigned)(key >> 52);
        const int b0 = (int)baseP1[bin], b1 = (int)baseP1[bin+1];
        int rank = 0;
        for (int j = b0; j < b1; ++j) rank += (P1[j] < key) ? 1 : 0;
        P1s[b0 + rank] = (unsigned)(key & 0xffffffffu);
    } else if (gg < 2*POOLN) {
        const int e = gg - POOLN;
        const unsigned long long key = P2[e];
        const unsigned int bin = (unsigned)(key >> 52);
        const int b0 = (int)baseP2[bin], b1 = (int)baseP2[bin+1];
        int rank = 0;
        for (int j = b0; j < b1; ++j) rank += (P2[j] < key) ? 1 : 0;
        P2s[b0 + rank] = (unsigned)(key & 0xffffffffu);
    }
}

// ---------------------------------------------------------------------------
__global__ __launch_bounds__(256) void k_final(
    const float* __restrict__ logits, const unsigned int* __restrict__ As,
    const unsigned int* __restrict__ P1s, const unsigned int* __restrict__ P2s,
    const float* __restrict__ partial, float* __restrict__ out2)
{
    __shared__ float red[256];
    const int t = threadIdx.x;
    float s = 0.0f;
    for (int j = t; j < N_POSA; j += 256) {
        const unsigned int i2 = P2s[j];
        const unsigned int r  = P1s[i2];
        const unsigned int i  = As[r];
        const float l0 = logits[(size_t)(N_POSA+i)*2+0];
        const float l1 = logits[(size_t)(N_POSA+i)*2+1];
        const float m = fmaxf(l0, l1);
        s += (l0 - m) - logf(expf(l0-m) + expf(l1-m));
    }
    red[t] = s;
    __syncthreads();
    for (int off = 128; off > 0; off >>= 1) {
        if (t < off) red[t] += red[t+off];
        __syncthreads();
    }
    if (t == 0) {
        const float neg_loss = -red[0] / (float)N_POSA;
        const float pos_loss = -partial[0] / (float)N_POSA;
        out2[0] = 0.5f * (pos_loss + neg_loss);
        out2[1] = partial[1] / (float)(N_POSA*4);
    }
}

// ---------------------------------------------------------------------------
extern "C" void kernel_launch(void* const* d_in, const int* in_sizes, int n_in,
                              void* d_out, int out_size, void* d_ws, size_t ws_size,
                              hipStream_t stream)
{
    const float* f0     = (const float*)d_in[0];
    const float* f1     = (const float*)d_in[1];
    const float* f2     = (const float*)d_in[2];
    const float* f3     = (const float*)d_in[3];
    const float* rois   = (const float*)d_in[4];
    const int*   am     = (const int*)  d_in[5];
    const float* logits = (const float*)d_in[6];
    const float* pd     = (const float*)d_in[7];
    const float* td     = (const float*)d_in[8];
    float* out = (float*)d_out;

    char* ws = (char*)d_ws;
    unsigned long long* A      = (unsigned long long*)(ws);            // 262144
    unsigned long long* T1     = (unsigned long long*)(ws +  262144); // 160000
    unsigned long long* T2     = (unsigned long long*)(ws +  422144); // 160000
    unsigned long long* P1     = (unsigned long long*)(ws +  582144); // 160000
    unsigned long long* P2     = (unsigned long long*)(ws +  742144); // 160000
    unsigned int*       histA  = (unsigned int*)      (ws +  902144); // 32768
    unsigned int*       histP1 = (unsigned int*)      (ws +  934912); // 16384
    unsigned int*       histP2 = (unsigned int*)      (ws +  951296); // 16384
    unsigned int*       baseA  = (unsigned int*)      (ws +  967680); // 32832
    unsigned int*       resvA  = (unsigned int*)      (ws + 1000512); // 32768
    unsigned int*       baseP1 = (unsigned int*)      (ws + 1033344); // 16448
    unsigned int*       resvP1 = (unsigned int*)      (ws + 1049792); // 16384
    unsigned int*       baseP2 = (unsigned int*)      (ws + 1066240); // 16448
    unsigned int*       resvP2 = (unsigned int*)      (ws + 1082688); // 16384
    unsigned int*       sel    = (unsigned int*)      (ws + 1099136); // 64
    float*              prt    = (float*)             (ws + 1099200); // 64
    __hip_bfloat16*     tl     = (__hip_bfloat16*)    (ws + 1099264); // 44564480
    unsigned int*       As     = (unsigned int*)T1;
    unsigned int*       P1s    = (unsigned int*)T2;
    unsigned int*       P2s    = (unsigned int*)((char*)T2 + 80000);
    const size_t NEED = 1099264ull + TLELEMS * 2ull;
    const bool use_cl = (ws_size >= NEED);
    const int rcnt = use_cl ? NROIS : 0;

    // 1) zero hists + reservation counters
    k_zero<<<128, 256, 0, stream>>>(histA, resvA, resvP1, resvP2);

    // 2) transpose || prep (perm keys + hists + losses)
    k_trprep<<<(use_cl ? NTRBLK : 0) + NPREP, 256, 0, stream>>>(
        f0, f1, f2, f3, tl, T1, T2, histA, histP1, histP2,
        am, logits, pd, td, prt, use_cl ? NTRBLK : 0);

    if (!use_cl)
        k_roi<<<NROIS, 256, 0, stream>>>(f0, f1, f2, f3, rois, out);

    // 3) roi (all 4000) || scan || self-deriving scatter
    k_stage3<<<rcnt + 144, 256, 0, stream>>>(tl, rois, out, logits,
                                             T1, T2, A, P1, P2,
                                             histA, histP1, histP2,
                                             baseA, baseP1, baseP2,
                                             resvA, resvP1, resvP2, sel, rcnt);

    // 4) per-bin LDS counting-sort rank
    k_rank<<<NRANKA + NRANKP, 1024, 0, stream>>>(A, P1, P2, baseA, baseP1, baseP2,
                                                 sel, As, P1s, P2s);

    // 5) final scalars
    k_final<<<1, 256, 0, stream>>>(logits, As, P1s, P2s, prt,
                                   out + (size_t)NROIS*NCH*NBINS);
}